// Round 9
// baseline (248.103 us; speedup 1.0000x reference)
//
#include <hip/hip_runtime.h>
#include <math.h>

#define B     4096
#define ND    13
#define NS    26
#define NF    39
#define VOCAB 100000
#define NP    351      // l<=m pairs in 26x26
#define NPP   360      // padded to 8 chunks * 45
#define CHP   45       // p's per chunk
#define GSTR  28       // Gst row: [0..25]=Gs_j, [26]=A1s, [27]=lut bits
#define RPB   8
#define TPB   512
#define XSS   212

// ---------------- workspace layout (floats) ----------------
#define OFF_GST 0        // 360*28 = 10080
#define OFF_CST 10080    // 1
#define OFF_C2J 10088    // 26

// ---- single merged precompute kernel, 28 independent blocks ----
__global__ __launch_bounds__(256) void k_pre(const float* __restrict__ W0,
                                             const float* __restrict__ W1,
                                             const float* __restrict__ b0,
                                             const float* __restrict__ b1,
                                             const float* __restrict__ clw,
                                             float* __restrict__ Gst,
                                             float* __restrict__ cst,
                                             float* __restrict__ c2j) {
    int blk = blockIdx.x, tid = threadIdx.x;
    if (blk < 26) {
        int j = blk;
        __shared__ float vh[2][128];
        __shared__ float vj[128];
        __shared__ float c2r[2];
        {
            int i = tid & 127, h = tid >> 7;
            const float* wp = W1 + (long)(h * 64) * 3328 + i * 26 + j;
            float acc = 0.f;
#pragma unroll 8
            for (int o = 0; o < 64; o++) acc += clw[128 + h * 64 + o] * wp[o * 3328];
            vh[h][i] = acc;
        }
        __syncthreads();
        if (tid < 128) {
            float vv = vh[0][tid] + vh[1][tid];
            vj[tid] = vv;
            float c = vv * b0[tid];
            for (int off = 32; off; off >>= 1) c += __shfl_down(c, off, 64);
            if ((tid & 63) == 0) c2r[tid >> 6] = c;
        }
        __syncthreads();
        if (tid == 0) c2j[j] = c2r[0] + c2r[1];
        for (int p = tid; p < NPP; p += 256) {
            float g = 0.f;
            if (p < NP) {
                int l = 0, rem = p;
                while (rem >= NS - l) { rem -= NS - l; l++; }
                int m = l + rem;
                float sym = (l != m) ? 1.f : 0.f;
                const float* wa = W0 + l * 26 + m;
                const float* wb = W0 + m * 26 + l;
#pragma unroll 8
                for (int i = 0; i < 128; i++)
                    g += vj[i] * (wa[i * 676] + sym * wb[i * 676]);
            }
            Gst[p * GSTR + j] = g;
        }
    } else if (blk == 26) {
        for (int p = tid; p < NPP; p += 256) {
            float a = 0.f; int lmbits = 0;
            if (p < NP) {
                int l = 0, rem = p;
                while (rem >= NS - l) { rem -= NS - l; l++; }
                int m = l + rem;
                float sym = (l != m) ? 1.f : 0.f;
                const float* wa = W0 + l * 26 + m;
                const float* wb = W0 + m * 26 + l;
#pragma unroll 8
                for (int o = 0; o < 128; o++)
                    a += clw[o] * (wa[o * 676] + sym * wb[o * 676]);
                lmbits = (l << 5) | m;
            }
            Gst[p * GSTR + 26] = a;
            Gst[p * GSTR + 27] = __int_as_float(lmbits);
        }
    } else {
        __shared__ float red[2];
        float c = 0.f;
        if (tid < 128) {
            c = clw[tid] * b0[tid] + clw[128 + tid] * b1[tid];
            for (int off = 32; off; off >>= 1) c += __shfl_down(c, off, 64);
            if ((tid & 63) == 0) red[tid >> 6] = c;
        }
        __syncthreads();
        if (tid == 0) cst[0] = 8.f * (red[0] + red[1]);
    }
}

// ---- fused main: 8 rows/block, 512 threads, 3 barriers total ----
// bar1 after {gather -> xs AND inT directly}; then CIN + Layer1 run as ONE
// barrier-free stretch (waves desync); full-K everywhere (no pbuf/combines);
// L3+L4 collapse to one wave per row with shuffle reduce + direct output.
__global__ __launch_bounds__(512, 4) void k_main(
    const float* __restrict__ inputs, const float* __restrict__ tables,
    const float* __restrict__ lW, const float* __restrict__ lb,
    const float* __restrict__ Gst, const float* __restrict__ c2j,
    const float* __restrict__ cst,
    const float* __restrict__ dW1, const float* __restrict__ db1,
    const float* __restrict__ dW2, const float* __restrict__ db2,
    const float* __restrict__ dW3, const float* __restrict__ db3,
    const float* __restrict__ dW4, const float* __restrict__ db4,
    const float* __restrict__ clb,
    float* __restrict__ out) {
    __shared__ float xs[RPB][XSS];           // emb per row, CIN layout (6784 B)
    __shared__ float inTf[221 * 8];          // DNN input transposed [c*8+r] (7072 B); h2T alias
    __shared__ float h1Tf[256 * 12];         // stride 12: bank-rotating (12288 B)
    __shared__ float lin_s[RPB];
    __shared__ float redbuf[8][RPB];

    float* h2Tf = inTf;                      // alias: inT dead after L1 (bar2)

    int tid = threadIdx.x;
    int b0r = blockIdx.x * RPB;

    // ---- P0: gather -> xs AND inT; dense cols -> inT; linear term ----
    if (tid < RPB * NS) {                    // 208 threads
        int r = tid / NS, f = tid - r * NS;
        int idx = (int)inputs[(b0r + r) * NF + ND + f];
        const float4* src = (const float4*)(tables + ((long)f * VOCAB + idx) * 8);
        float4 a = src[0], b4 = src[1];
        *(float4*)&xs[r][f * 8] = a;
        *(float4*)&xs[r][f * 8 + 4] = b4;
        int cb = (ND + f * 8) * 8 + r;       // inT[(13+f*8+j)*8 + r]
        inTf[cb]      = a.x;  inTf[cb + 8]   = a.y;
        inTf[cb + 16] = a.z;  inTf[cb + 24]  = a.w;
        inTf[cb + 32] = b4.x; inTf[cb + 40]  = b4.y;
        inTf[cb + 48] = b4.z; inTf[cb + 56]  = b4.w;
    } else if (tid < 208 + ND * RPB) {       // 104 threads: dense cols
        int t = tid - 208;
        int c = t >> 3, r = t & 7;
        inTf[c * 8 + r] = inputs[(b0r + r) * NF + c];
    }
    if (tid >= 496 && tid < 496 + RPB) {
        int r = tid - 496;
        float acc = lb[0];
        for (int c = 0; c < NF; c++) acc += inputs[(b0r + r) * NF + c] * lW[c];
        lin_s[r] = acc;
    }
    __syncthreads();                         // bar1

    // ---- P1: CIN (per-wave chunk) -- rolls straight into L1, NO barrier ----
    {
        int w = tid >> 6;
        int wu = __builtin_amdgcn_readfirstlane(w);
        int lane = tid & 63;
        int row = lane >> 3, k = lane & 7;
        const float4* g4 = (const float4*)Gst + wu * CHP * 7;  // uniform -> s_load
        const float* xrow = &xs[row][0];
        float csel = (wu == 0) ? 1.f : 0.f;
        float t[27];
#pragma unroll
        for (int j = 0; j < 27; j++) t[j] = 0.f;
#pragma unroll 3
        for (int pi = 0; pi < CHP; pi++) {
            float4 g6 = g4[pi * 7 + 6];
            int lm = __float_as_int(g6.w);
            float q = xrow[(lm >> 5) * 8 + k] * xrow[(lm & 31) * 8 + k];
            float4 g0 = g4[pi * 7 + 0], g1 = g4[pi * 7 + 1];
            float4 g2 = g4[pi * 7 + 2], g3 = g4[pi * 7 + 3];
            float4 g4v = g4[pi * 7 + 4], g5 = g4[pi * 7 + 5];
            t[0]  += g0.x * q; t[1]  += g0.y * q; t[2]  += g0.z * q; t[3]  += g0.w * q;
            t[4]  += g1.x * q; t[5]  += g1.y * q; t[6]  += g1.z * q; t[7]  += g1.w * q;
            t[8]  += g2.x * q; t[9]  += g2.y * q; t[10] += g2.z * q; t[11] += g2.w * q;
            t[12] += g3.x * q; t[13] += g3.y * q; t[14] += g3.z * q; t[15] += g3.w * q;
            t[16] += g4v.x * q; t[17] += g4v.y * q; t[18] += g4v.z * q; t[19] += g4v.w * q;
            t[20] += g5.x * q; t[21] += g5.y * q; t[22] += g5.z * q; t[23] += g5.w * q;
            t[24] += g6.x * q; t[25] += g6.y * q; t[26] += g6.z * q;
        }
        float part = t[26];
#pragma unroll
        for (int j = 0; j < 26; j++) {
            float xv = xrow[j * 8 + k];
            part += (t[j] + csel * c2j[j]) * xv;
        }
        part += __shfl_xor(part, 1, 64);
        part += __shfl_xor(part, 2, 64);
        part += __shfl_xor(part, 4, 64);
        if (k == 0) redbuf[w][row] = part;
    }
    // (no barrier: L1 reads only inT, written before bar1; redbuf consumed after bar2)

    // ---- P2: Layer1 221->256 full-K. o=tid&255, g=tid>>8 -> rows 4g..4g+3 ----
    {
        int o = tid & 255, g = tid >> 8;
        const float* ip = inTf + 4 * g;
        float4 A = make_float4(0.f, 0.f, 0.f, 0.f);
#pragma unroll 4
        for (int c = 0; c < 221; c++) {
            float wv = dW1[c * 256 + o];
            float4 iv = *(const float4*)&ip[c * 8];
            A.x += iv.x * wv; A.y += iv.y * wv; A.z += iv.z * wv; A.w += iv.w * wv;
        }
        float bb = db1[o];
        float4 S;
        S.x = fmaxf(A.x + bb, 0.f); S.y = fmaxf(A.y + bb, 0.f);
        S.z = fmaxf(A.z + bb, 0.f); S.w = fmaxf(A.w + bb, 0.f);
        *(float4*)&h1Tf[o * 12 + 4 * g] = S;
    }
    __syncthreads();                         // bar2

    // ---- P3: Layer2 256->128 full-K. o=tid&127, g=tid>>7 -> rows 2g,2g+1 ----
    {
        int o = tid & 127, g = tid >> 7;
        const float* ip = h1Tf + 2 * g;
        float a0 = 0.f, a1 = 0.f;
#pragma unroll 4
        for (int c = 0; c < 256; c++) {
            float wv = dW2[c * 128 + o];
            float2 iv = *(const float2*)&ip[c * 12];
            a0 += iv.x * wv; a1 += iv.y * wv;
        }
        float bb = db2[o];
        a0 = fmaxf(a0 + bb, 0.f); a1 = fmaxf(a1 + bb, 0.f);
        h2Tf[o * 12 + 2 * g]     = a0;       // h2T over dead inT (bar2 passed)
        h2Tf[o * 12 + 2 * g + 1] = a1;
    }
    __syncthreads();                         // bar3

    // ---- P4: Layer3 128->64 full-K + L4 + final + sigmoid. wave w -> row w ----
    {
        int o = tid & 63, g = tid >> 6;      // row = wave index
        float acc = 0.f;
#pragma unroll 4
        for (int c = 0; c < 128; c++) {
            float wv = dW3[c * 64 + o];
            float hv = h2Tf[c * 12 + g];     // wave-uniform addr -> broadcast
            acc += hv * wv;
        }
        float h3 = fmaxf(acc + db3[o], 0.f) * dW4[o];
        h3 += __shfl_xor(h3, 1, 64);
        h3 += __shfl_xor(h3, 2, 64);
        h3 += __shfl_xor(h3, 4, 64);
        h3 += __shfl_xor(h3, 8, 64);
        h3 += __shfl_xor(h3, 16, 64);
        h3 += __shfl_xor(h3, 32, 64);
        if (o == 0) {
            float scin = cst[0];
#pragma unroll
            for (int w2 = 0; w2 < 8; w2++) scin += redbuf[w2][g];
            float dense = fmaxf(h3 + db4[0], 0.f);
            float cin = fmaxf(scin + clb[0], 0.f);
            float x = lin_s[g] + cin + dense;
            out[b0r + g] = 1.f / (1.f + expf(-x));
        }
    }
}

extern "C" void kernel_launch(void* const* d_in, const int* in_sizes, int n_in,
                              void* d_out, int out_size, void* d_ws, size_t ws_size,
                              hipStream_t stream) {
    const float* inputs = (const float*)d_in[0];
    const float* tables = (const float*)d_in[1];
    const float* lW     = (const float*)d_in[2];
    const float* lb     = (const float*)d_in[3];
    const float* W0     = (const float*)d_in[4];
    const float* b0     = (const float*)d_in[5];
    const float* W1c    = (const float*)d_in[6];
    const float* b1c    = (const float*)d_in[7];
    const float* clw    = (const float*)d_in[8];
    const float* clb    = (const float*)d_in[9];
    const float* dW1    = (const float*)d_in[10];
    const float* db1    = (const float*)d_in[11];
    const float* dW2    = (const float*)d_in[12];
    const float* db2    = (const float*)d_in[13];
    const float* dW3    = (const float*)d_in[14];
    const float* db3    = (const float*)d_in[15];
    const float* dW4    = (const float*)d_in[16];
    const float* db4    = (const float*)d_in[17];

    float* ws   = (float*)d_ws;
    float* Gst  = ws + OFF_GST;
    float* cst  = ws + OFF_CST;
    float* c2j  = ws + OFF_C2J;

    k_pre<<<28, 256, 0, stream>>>(W0, W1c, b0, b1c, clw, Gst, cst, c2j);
    k_main<<<B / RPB, TPB, 0, stream>>>(inputs, tables, lW, lb, Gst, c2j, cst,
                                        dW1, db1, dW2, db2, dW3, db3, dW4, db4, clb,
                                        (float*)d_out);
}